// Round 4
// baseline (456.961 us; speedup 1.0000x reference)
//
#include <hip/hip_runtime.h>

#define B_ROWS 4096
#define K_DIM  40960
#define H_DIM  128
#define BM     128
#define BK     64
#define KSPLIT 4
#define KCHUNK (K_DIM / KSPLIT)   // 10240
#define NT     (KCHUNK / BK)      // 160 (even)
#define MT     (B_ROWS / BM)      // 32

typedef __attribute__((ext_vector_type(4))) float f32x4;
typedef __attribute__((ext_vector_type(8))) short short8;

static_assert(KSPLIT * KCHUNK == K_DIM, "ksplit");
static_assert((NT & 1) == 0, "NT even");

// fallback accumulator (atomic path) if ws too small: [2][B_ROWS][H_DIM]
__device__ float g_acc[2u * B_ROWS * H_DIM];

__device__ __forceinline__ unsigned pkbf(float a, float b) {
  // pack 2 f32 -> 2 bf16 (RTN-even), inputs finite
  unsigned ua = __float_as_uint(a), ub = __float_as_uint(b);
  ua = (ua + 0x7fffu + ((ua >> 16) & 1u)) >> 16;
  ub = (ub + 0x7fffu + ((ub >> 16) & 1u)) & 0xffff0000u;
  return ua | ub;
}

__device__ __forceinline__ short8 pk8f4(float4 a, float4 b) {
  union { unsigned u[4]; short8 s; } r;
  r.u[0] = pkbf(a.x, a.y);
  r.u[1] = pkbf(a.z, a.w);
  r.u[2] = pkbf(b.x, b.y);
  r.u[3] = pkbf(b.z, b.w);
  return r.s;
}

// f32 tiles staged direct global->LDS (global_load_lds, 16B), double-buffered.
// Counted s_waitcnt vmcnt(8): the next tile's 8 loads stay in flight across
// both barriers (T3/T4). bf16 conversion happens at fragment-read time.
// LDS XOR-swizzle via pre-swizzled GLOBAL source (linear LDS dest), rule #21.
template <bool ATOMIC>
__global__ __launch_bounds__(512, 2) void nnue_stage1(
    const float* __restrict__ x1, const float* __restrict__ x2,
    const float* __restrict__ wus, const float* __restrict__ wthem,
    float* __restrict__ part) {
  __shared__ float ldsA[2][BM][BK];     // 64 KB
  __shared__ float ldsB[2][H_DIM][BK];  // 64 KB

  const int t = threadIdx.x;

  // grid = 256 = 1 block/CU. bid&7 -> XCD (round-robin dispatch): all 32
  // blocks of an XCD share one (mat,ks) weight chunk (L2-resident).
  const int bid = blockIdx.x;   // 0..255
  const int g   = bid & 7;      // (mat,ks) group
  const int mt  = bid >> 3;     // 0..31
  const int mat = g & 1;
  const int ks  = g >> 1;       // 0..3

  const float* __restrict__ X = mat ? x2 : x1;
  const float* __restrict__ W = mat ? wthem : wus;
  const size_t kb0 = (size_t)ks * KCHUNK;

  const int l = t & 63;
  const int w = t >> 6;  // wave 0..7

  // ---- staging source pointers: call q covers rows (w*4+q)*4 + (l>>4),
  // 16B-chunk slot s=l&15 holds global chunk s^(row&7)  (inverse swizzle)
  const float* gAq[4];
  const float* gBq[4];
  #pragma unroll
  for (int q = 0; q < 4; ++q) {
    const int r = (w * 4 + q) * 4 + (l >> 4);   // 0..127
    const int c = (l & 15) ^ (r & 7);           // swizzled 16B chunk
    gAq[q] = X + ((size_t)(mt * BM + r)) * K_DIM + kb0 + c * 4;
    gBq[q] = W + (size_t)r * K_DIM + kb0 + c * 4;
  }

  // ---- fragment read byte offsets (kb=0,d=0; derive others via ^16/^128)
  const int wr  = w >> 2;   // 0..1 (64 rows)
  const int wc  = w & 3;    // 0..3 (32 cols)
  const int fr  = l & 15;
  const int lhi = l >> 4;   // 0..3

  int offA[4], offB[2];
  #pragma unroll
  for (int i = 0; i < 4; ++i) {
    const int ra = wr * 64 + i * 16 + fr;
    offA[i] = ra * 256 + (((lhi * 2) ^ (ra & 7)) << 4);
  }
  #pragma unroll
  for (int j = 0; j < 2; ++j) {
    const int cb = wc * 32 + j * 16 + fr;
    offB[j] = cb * 256 + (((lhi * 2) ^ (cb & 7)) << 4);
  }

  f32x4 acc[4][2] = {};

#define GLOAD(g_, l_)                                                       \
  __builtin_amdgcn_global_load_lds(                                         \
      (const __attribute__((address_space(1))) void*)(g_),                  \
      (__attribute__((address_space(3))) void*)(l_), 16, 0, 0)

  // 8 loads per thread per tile (4 A + 4 B); LDS dest is wave-uniform base
#define ISSUE(buf_, kf_)                                                    \
  do {                                                                      \
    _Pragma("unroll") for (int q = 0; q < 4; ++q) {                         \
      GLOAD(gAq[q] + (kf_), &ldsA[buf_][(w * 4 + q) * 4][0]);               \
      GLOAD(gBq[q] + (kf_), &ldsB[buf_][(w * 4 + q) * 4][0]);               \
    }                                                                       \
  } while (0)

#define COMPUTE(buf_)                                                       \
  do {                                                                      \
    const char* bA = (const char*)(&ldsA[buf_][0][0]);                      \
    const char* bB = (const char*)(&ldsB[buf_][0][0]);                      \
    _Pragma("unroll") for (int kb = 0; kb < 2; ++kb) {                      \
      const int kx = kb * 128;                                              \
      short8 af[4], bg[2];                                                  \
      _Pragma("unroll") for (int i = 0; i < 4; ++i) {                       \
        float4 u = *(const float4*)(bA + (offA[i] ^ kx));                   \
        float4 v = *(const float4*)(bA + (offA[i] ^ kx ^ 16));              \
        af[i] = pk8f4(u, v);                                                \
      }                                                                     \
      _Pragma("unroll") for (int j = 0; j < 2; ++j) {                       \
        float4 u = *(const float4*)(bB + (offB[j] ^ kx));                   \
        float4 v = *(const float4*)(bB + (offB[j] ^ kx ^ 16));              \
        bg[j] = pk8f4(u, v);                                                \
      }                                                                     \
      _Pragma("unroll") for (int i = 0; i < 4; ++i)                         \
          _Pragma("unroll") for (int j = 0; j < 2; ++j)                     \
              acc[i][j] = __builtin_amdgcn_mfma_f32_16x16x32_bf16(          \
                  af[i], bg[j], acc[i][j], 0, 0, 0);                        \
    }                                                                       \
  } while (0)

#define WAIT_BAR(n_)                                                        \
  do {                                                                      \
    asm volatile("s_waitcnt vmcnt(" #n_ ")" ::: "memory");                  \
    __builtin_amdgcn_s_barrier();                                           \
    __builtin_amdgcn_sched_barrier(0);                                      \
  } while (0)

  // prologue: tiles 0,1 in flight
  ISSUE(0, 0);
  ISSUE(1, 64);

  int kf = 0;
  for (int kt = 0; kt < NT - 2; ++kt, kf += 64) {
    const int buf = kt & 1;
    WAIT_BAR(8);              // tile kt's 8 loads done; kt+1's still flying
    COMPUTE(buf);
    __builtin_amdgcn_sched_barrier(0);
    __builtin_amdgcn_s_barrier();   // all waves done reading buf
    ISSUE(buf, kf + 128);           // tile kt+2 -> buf (overwrites safely)
  }
  // tile NT-2
  WAIT_BAR(8);
  COMPUTE((NT - 2) & 1);
  __builtin_amdgcn_sched_barrier(0);
  // tile NT-1 (drain)
  WAIT_BAR(0);
  COMPUTE((NT - 1) & 1);

#undef GLOAD
#undef ISSUE
#undef COMPUTE
#undef WAIT_BAR

  // ---- epilogue: C/D layout col=lane&15, row=(lane>>4)*4+reg (m89-verified)
  if (!ATOMIC) {
    float* dst = part + (((size_t)mat * KSPLIT + ks) * B_ROWS) * (size_t)H_DIM;
    #pragma unroll
    for (int i = 0; i < 4; ++i)
      #pragma unroll
      for (int j = 0; j < 2; ++j)
        #pragma unroll
        for (int r = 0; r < 4; ++r) {
          const int rowg = mt * BM + wr * 64 + i * 16 + (lhi << 2) + r;
          const int colg = wc * 32 + j * 16 + fr;
          __builtin_nontemporal_store(acc[i][j][r],
                                      &dst[(size_t)rowg * H_DIM + colg]);
        }
  } else {
    float* dst = g_acc + (size_t)mat * B_ROWS * H_DIM;
    #pragma unroll
    for (int i = 0; i < 4; ++i)
      #pragma unroll
      for (int j = 0; j < 2; ++j)
        #pragma unroll
        for (int r = 0; r < 4; ++r) {
          const int rowg = mt * BM + wr * 64 + i * 16 + (lhi << 2) + r;
          const int colg = wc * 32 + j * 16 + fr;
          atomicAdd(&dst[(size_t)rowg * H_DIM + colg], acc[i][j][r]);
        }
  }
}

__global__ void nnue_zero_acc() {
  const unsigned i = blockIdx.x * 256 + threadIdx.x;
  if (i < 2u * B_ROWS * H_DIM) g_acc[i] = 0.f;
}

// one wave per output row; part==nullptr -> read g_acc (KS must be 1)
template <int KS>
__global__ __launch_bounds__(512) void nnue_stage2(
    const float* __restrict__ part, const float* __restrict__ w2,
    float* __restrict__ out) {
  const float* p = part ? part : (const float*)g_acc;
  const int t = threadIdx.x;
  const int l = t & 63, w = t >> 6;
  const int b = blockIdx.x * 8 + w;
  float a0 = 0.f, a1 = 0.f, a2 = 0.f, a3 = 0.f;
  #pragma unroll
  for (int ks = 0; ks < KS; ++ks) {
    const float* p0 = p + ((size_t)ks * B_ROWS + b) * H_DIM;
    const float* p1 = p + (((size_t)KS + ks) * B_ROWS + b) * H_DIM;
    a0 += __builtin_nontemporal_load(&p0[l]);
    a1 += __builtin_nontemporal_load(&p0[l + 64]);
    a2 += __builtin_nontemporal_load(&p1[l]);
    a3 += __builtin_nontemporal_load(&p1[l + 64]);
  }
  float sv = fmaxf(a0, 0.f) * w2[l] + fmaxf(a1, 0.f) * w2[l + 64] +
             fmaxf(a2, 0.f) * w2[l + 128] + fmaxf(a3, 0.f) * w2[l + 192];
  #pragma unroll
  for (int off = 32; off; off >>= 1) sv += __shfl_xor(sv, off, 64);
  if (l == 0) out[b] = sv;
}

extern "C" void kernel_launch(void* const* d_in, const int* in_sizes, int n_in,
                              void* d_out, int out_size, void* d_ws,
                              size_t ws_size, hipStream_t stream) {
  const float* x1    = (const float*)d_in[0];
  const float* x2    = (const float*)d_in[1];
  // d_in[2] = turn (unused by reference)
  const float* wus   = (const float*)d_in[3];
  const float* wthem = (const float*)d_in[4];
  const float* w2    = (const float*)d_in[5];
  float* out = (float*)d_out;

  const size_t PART_BYTES =
      2ull * KSPLIT * B_ROWS * H_DIM * sizeof(float);  // 16.8 MB

  if (ws_size >= PART_BYTES) {
    float* part = (float*)d_ws;
    nnue_stage1<false><<<MT * KSPLIT * 2, 512, 0, stream>>>(x1, x2, wus, wthem,
                                                            part);
    nnue_stage2<KSPLIT><<<B_ROWS / 8, 512, 0, stream>>>(part, w2, out);
  } else {
    nnue_zero_acc<<<(2 * B_ROWS * H_DIM + 255) / 256, 256, 0, stream>>>();
    nnue_stage1<true><<<MT * KSPLIT * 2, 512, 0, stream>>>(x1, x2, wus, wthem,
                                                           nullptr);
    nnue_stage2<1><<<B_ROWS / 8, 512, 0, stream>>>(nullptr, w2, out);
  }
}

// Round 5
// 317.441 us; speedup vs baseline: 1.4395x; 1.4395x over previous
//
#include <hip/hip_runtime.h>

#define B_ROWS 4096
#define K_DIM  40960
#define H_DIM  128
#define BM     64
#define BK     64
#define KSPLIT 4
#define KCHUNK (K_DIM / KSPLIT)   // 10240
#define NT     (KCHUNK / BK)      // 160 (even)
#define MT     (B_ROWS / BM)      // 64

typedef __attribute__((ext_vector_type(4))) float f32x4;
typedef __attribute__((ext_vector_type(8))) short short8;

static_assert(KSPLIT * KCHUNK == K_DIM, "ksplit");
static_assert((NT & 1) == 0, "NT even");

// fallback accumulator (atomic path) if ws too small: [2][B_ROWS][H_DIM]
__device__ float g_acc[2u * B_ROWS * H_DIM];

__device__ __forceinline__ unsigned pkbf(float a, float b) {
  // pack 2 f32 -> 2 bf16 (RTN-even), inputs finite
  unsigned ua = __float_as_uint(a), ub = __float_as_uint(b);
  ua = (ua + 0x7fffu + ((ua >> 16) & 1u)) >> 16;
  ub = (ub + 0x7fffu + ((ub >> 16) & 1u)) & 0xffff0000u;
  return ua | ub;
}

// R2 structure (reg-staged bf16, write-side XOR swizzle, 2 blocks/CU) with a
// 2-tile-deep register pipeline: STAGE(t) consumes loads issued at t-2, so the
// compiler's auto s_waitcnt is a counted vmcnt(6) (set t+1 still in flight) --
// the HBM stream never drains at a barrier (T4 via register deps).
// BM=64 keeps 2 register sets + acc under the 128-VGPR/2-blocks cap.
template <bool ATOMIC>
__global__ __launch_bounds__(512, 4) void nnue_stage1(
    const float* __restrict__ x1, const float* __restrict__ x2,
    const float* __restrict__ wus, const float* __restrict__ wthem,
    float* __restrict__ part) {
  __shared__ ushort ldsA[2][BM][BK];     // 16 KB
  __shared__ ushort ldsB[2][H_DIM][BK];  // 32 KB

  const int t = threadIdx.x;

  // grid 512; XCD = bid&7 (round-robin dispatch): all 64 blocks of one XCD
  // share one (mat,ks) weight chunk (5.2 MB -> L2+L3 resident).
  const int bid = blockIdx.x;   // 0..511
  const int g   = bid & 7;
  const int mt  = bid >> 3;     // 0..63
  const int mat = g & 1;
  const int ks  = g >> 1;       // 0..3

  const float* __restrict__ X = mat ? x2 : x1;
  const float* __restrict__ W = mat ? wthem : wus;
  const size_t kb0 = (size_t)ks * KCHUNK;

  // ---- staging ownership: float4 id e = t + 512k; row = e>>4, col16 = t&15
  const int r0 = t >> 4;         // 0..31
  const int c0 = (t & 15) * 4;   // f32 col offset in BK

  const float* gA0 = X + (size_t)(mt * BM + r0) * K_DIM + kb0 + c0;
  const float* gA1 = gA0 + (size_t)32 * K_DIM;
  const float* gB0 = W + (size_t)r0 * K_DIM + kb0 + c0;

  // LDS write byte offset (bf16, row stride 128 B, XOR-swizzled 16B slots)
  const int wb0 =
      r0 * 128 + (((((t & 15) >> 1)) ^ (r0 & 7)) << 4) + ((t & 1) * 8);

  // ---- fragment read offsets: 8 waves = 2M x 4N, wave tile 32x32
  const int l   = t & 63;
  const int w   = t >> 6;
  const int wr  = w >> 2;   // 0..1
  const int wc  = w & 3;    // 0..3
  const int fr  = l & 15;
  const int lhi = l >> 4;   // 0..3

  int offA[2], offB[2];
  #pragma unroll
  for (int i = 0; i < 2; ++i) {
    const int ra = wr * 32 + i * 16 + fr;
    offA[i] = ra * 128 + ((lhi ^ (ra & 7)) << 4);   // kb=1 via ^64
  }
  #pragma unroll
  for (int j = 0; j < 2; ++j) {
    const int cb = wc * 32 + j * 16 + fr;
    offB[j] = cb * 128 + ((lhi ^ (cb & 7)) << 4);
  }

  f32x4 acc[2][2] = {};
  f32x4 s0[6], s1[6];  // two staging sets: [0..1]=A rows r0/r0+32, [2..5]=B

#define ISSUE(S_, kt_)                                                      \
  do {                                                                      \
    const size_t ko = (size_t)(kt_)*BK;                                     \
    S_[0] = __builtin_nontemporal_load((const f32x4*)(gA0 + ko));           \
    S_[1] = __builtin_nontemporal_load((const f32x4*)(gA1 + ko));           \
    S_[2] = *(const f32x4*)(gB0 + ko);                                      \
    S_[3] = *(const f32x4*)(gB0 + ko + (size_t)32 * K_DIM);                 \
    S_[4] = *(const f32x4*)(gB0 + ko + (size_t)64 * K_DIM);                 \
    S_[5] = *(const f32x4*)(gB0 + ko + (size_t)96 * K_DIM);                 \
  } while (0)

#define PK2(v_) \
  { pkbf((v_)[0], (v_)[1]), pkbf((v_)[2], (v_)[3]) }

#define STAGE(S_, buf_)                                                     \
  do {                                                                      \
    char* bA = (char*)ldsA + (buf_)*8192 + wb0;                             \
    char* bB = (char*)ldsB + (buf_)*16384 + wb0;                            \
    uint2 u0 = PK2(S_[0]); *(uint2*)(bA) = u0;                              \
    uint2 u1 = PK2(S_[1]); *(uint2*)(bA + 4096) = u1;                       \
    uint2 u2 = PK2(S_[2]); *(uint2*)(bB) = u2;                              \
    uint2 u3 = PK2(S_[3]); *(uint2*)(bB + 4096) = u3;                       \
    uint2 u4 = PK2(S_[4]); *(uint2*)(bB + 8192) = u4;                       \
    uint2 u5 = PK2(S_[5]); *(uint2*)(bB + 12288) = u5;                      \
  } while (0)

#define COMPUTE(buf_)                                                       \
  do {                                                                      \
    const char* bA = (const char*)ldsA + (buf_)*8192;                       \
    const char* bB = (const char*)ldsB + (buf_)*16384;                      \
    _Pragma("unroll") for (int kb = 0; kb < 2; ++kb) {                      \
      const int kx = kb * 64;                                               \
      short8 af[2], bg[2];                                                  \
      _Pragma("unroll") for (int i = 0; i < 2; ++i)                         \
          af[i] = *(const short8*)(bA + (offA[i] ^ kx));                    \
      _Pragma("unroll") for (int j = 0; j < 2; ++j)                         \
          bg[j] = *(const short8*)(bB + (offB[j] ^ kx));                    \
      _Pragma("unroll") for (int i = 0; i < 2; ++i)                         \
          _Pragma("unroll") for (int j = 0; j < 2; ++j)                     \
              acc[i][j] = __builtin_amdgcn_mfma_f32_16x16x32_bf16(          \
                  af[i], bg[j], acc[i][j], 0, 0, 0);                        \
    }                                                                       \
  } while (0)

  // prologue: 2 tiles in flight
  ISSUE(s0, 0);
  ISSUE(s1, 1);

  for (int kt = 0; kt < NT - 2; kt += 2) {
    STAGE(s0, 0);          // waits (counted) on s0; s1 stays in flight
    __syncthreads();
    ISSUE(s0, kt + 2);
    COMPUTE(0);
    STAGE(s1, 1);
    __syncthreads();
    ISSUE(s1, kt + 3);
    COMPUTE(1);
  }
  STAGE(s0, 0);
  __syncthreads();
  COMPUTE(0);
  STAGE(s1, 1);
  __syncthreads();
  COMPUTE(1);

#undef ISSUE
#undef PK2
#undef STAGE
#undef COMPUTE

  // ---- epilogue: C/D layout col=lane&15, row=(lane>>4)*4+reg (m89-verified)
  if (!ATOMIC) {
    float* dst = part + (((size_t)mat * KSPLIT + ks) * B_ROWS) * (size_t)H_DIM;
    #pragma unroll
    for (int i = 0; i < 2; ++i)
      #pragma unroll
      for (int j = 0; j < 2; ++j)
        #pragma unroll
        for (int r = 0; r < 4; ++r) {
          const int rowg = mt * BM + wr * 32 + i * 16 + (lhi << 2) + r;
          const int colg = wc * 32 + j * 16 + fr;
          __builtin_nontemporal_store(acc[i][j][r],
                                      &dst[(size_t)rowg * H_DIM + colg]);
        }
  } else {
    float* dst = g_acc + (size_t)mat * B_ROWS * H_DIM;
    #pragma unroll
    for (int i = 0; i < 2; ++i)
      #pragma unroll
      for (int j = 0; j < 2; ++j)
        #pragma unroll
        for (int r = 0; r < 4; ++r) {
          const int rowg = mt * BM + wr * 32 + i * 16 + (lhi << 2) + r;
          const int colg = wc * 32 + j * 16 + fr;
          atomicAdd(&dst[(size_t)rowg * H_DIM + colg], acc[i][j][r]);
        }
  }
}

__global__ void nnue_zero_acc() {
  const unsigned i = blockIdx.x * 256 + threadIdx.x;
  if (i < 2u * B_ROWS * H_DIM) g_acc[i] = 0.f;
}

// one wave per output row; part==nullptr -> read g_acc (KS must be 1)
template <int KS>
__global__ __launch_bounds__(512) void nnue_stage2(
    const float* __restrict__ part, const float* __restrict__ w2,
    float* __restrict__ out) {
  const float* p = part ? part : (const float*)g_acc;
  const int t = threadIdx.x;
  const int l = t & 63, w = t >> 6;
  const int b = blockIdx.x * 8 + w;
  float a0 = 0.f, a1 = 0.f, a2 = 0.f, a3 = 0.f;
  #pragma unroll
  for (int ks = 0; ks < KS; ++ks) {
    const float* p0 = p + ((size_t)ks * B_ROWS + b) * H_DIM;
    const float* p1 = p + (((size_t)KS + ks) * B_ROWS + b) * H_DIM;
    a0 += __builtin_nontemporal_load(&p0[l]);
    a1 += __builtin_nontemporal_load(&p0[l + 64]);
    a2 += __builtin_nontemporal_load(&p1[l]);
    a3 += __builtin_nontemporal_load(&p1[l + 64]);
  }
  float sv = fmaxf(a0, 0.f) * w2[l] + fmaxf(a1, 0.f) * w2[l + 64] +
             fmaxf(a2, 0.f) * w2[l + 128] + fmaxf(a3, 0.f) * w2[l + 192];
  #pragma unroll
  for (int off = 32; off; off >>= 1) sv += __shfl_xor(sv, off, 64);
  if (l == 0) out[b] = sv;
}

extern "C" void kernel_launch(void* const* d_in, const int* in_sizes, int n_in,
                              void* d_out, int out_size, void* d_ws,
                              size_t ws_size, hipStream_t stream) {
  const float* x1    = (const float*)d_in[0];
  const float* x2    = (const float*)d_in[1];
  // d_in[2] = turn (unused by reference)
  const float* wus   = (const float*)d_in[3];
  const float* wthem = (const float*)d_in[4];
  const float* w2    = (const float*)d_in[5];
  float* out = (float*)d_out;

  const size_t PART_BYTES =
      2ull * KSPLIT * B_ROWS * H_DIM * sizeof(float);  // 16.8 MB

  if (ws_size >= PART_BYTES) {
    float* part = (float*)d_ws;
    nnue_stage1<false><<<MT * KSPLIT * 2, 512, 0, stream>>>(x1, x2, wus, wthem,
                                                            part);
    nnue_stage2<KSPLIT><<<B_ROWS / 8, 512, 0, stream>>>(part, w2, out);
  } else {
    nnue_zero_acc<<<(2 * B_ROWS * H_DIM + 255) / 256, 256, 0, stream>>>();
    nnue_stage1<true><<<MT * KSPLIT * 2, 512, 0, stream>>>(x1, x2, wus, wthem,
                                                           nullptr);
    nnue_stage2<1><<<B_ROWS / 8, 512, 0, stream>>>(nullptr, w2, out);
  }
}

// Round 6
// 267.535 us; speedup vs baseline: 1.7080x; 1.1865x over previous
//
#include <hip/hip_runtime.h>

#define B_ROWS 4096
#define K_DIM  40960
#define H_DIM  128
#define BM     128
#define BK     64
#define KSPLIT 8
#define KCHUNK (K_DIM / KSPLIT)   // 5120
#define NT     (KCHUNK / BK)      // 80 (even)
#define MT     (B_ROWS / BM)      // 32

typedef __attribute__((ext_vector_type(4))) float f32x4;
typedef __attribute__((ext_vector_type(8))) short short8;

static_assert(KSPLIT * KCHUNK == K_DIM, "ksplit");
static_assert((NT & 1) == 0, "NT even");

// fallback accumulator (atomic path) if ws too small: [2][B_ROWS][H_DIM]
__device__ float g_acc[2u * B_ROWS * H_DIM];

__device__ __forceinline__ unsigned pkbf(float a, float b) {
  // pack 2 f32 -> 2 bf16 (RTN-even), inputs finite
  unsigned ua = __float_as_uint(a), ub = __float_as_uint(b);
  ua = (ua + 0x7fffu + ((ua >> 16) & 1u)) >> 16;
  ub = (ub + 0x7fffu + ((ub >> 16) & 1u)) & 0xffff0000u;
  return ua | ub;
}

// R2 geometry (BM=128, KSPLIT=8: weight chunk 2.6MB fits one XCD's L2;
// 512 thr, 2 blocks/CU) + 2-tile-deep A register pipeline: STAGE_A(t)
// consumes HBM loads issued a full iteration (2 tiles) earlier, and at every
// counted wait the wave still has 8 loads in flight -- the HBM stream never
// drains. B (L2-resident) is 1-deep, issued right after its previous consume,
// covered by the COMPUTE phase (~400cy > L2 ~250cy).
template <bool ATOMIC>
__global__ __launch_bounds__(512, 4) void nnue_stage1(
    const float* __restrict__ x1, const float* __restrict__ x2,
    const float* __restrict__ wus, const float* __restrict__ wthem,
    float* __restrict__ part) {
  __shared__ ushort ldsA[2][BM][BK];     // 32 KB
  __shared__ ushort ldsB[2][H_DIM][BK];  // 32 KB

  const int t = threadIdx.x;

  // XCD decode: 32 blocks sharing a (mat,ks) weight chunk -> same XCD
  const int bid  = blockIdx.x;             // 0..511
  const int xcd  = bid & 7;
  const int slot = bid >> 3;               // 0..63
  const int g    = xcd + 8 * (slot >> 5);  // 0..15 group = (ks,mat)
  const int mt   = slot & 31;
  const int mat  = g & 1;
  const int ks   = g >> 1;

  const float* __restrict__ X = mat ? x2 : x1;
  const float* __restrict__ W = mat ? wthem : wus;
  const size_t kb0 = (size_t)ks * KCHUNK;

  // ---- staging ownership: thread t covers rows r0+32r (r=0..3), f32 col c0
  const int r0 = t >> 4;         // 0..31
  const int c0 = (t & 15) * 4;   // f32 col in BK

  const float* gA = X + (size_t)(mt * BM + r0) * K_DIM + kb0 + c0;
  const float* gB = W + (size_t)r0 * K_DIM + kb0 + c0;

  // LDS write byte offset (bf16 rows of 128B, XOR-swizzled 16B slots);
  // rows r0+32r share (row&7) so wb step is exactly r*4096.
  const int wb0 =
      r0 * 128 + ((((t & 15) >> 1) ^ (r0 & 7)) << 4) + ((t & 1) * 8);

  // ---- fragment read offsets: 8 waves = 2M x 4N, wave tile 64x32
  const int l   = t & 63;
  const int w   = t >> 6;
  const int wr  = w >> 2;   // 0..1
  const int wc  = w & 3;    // 0..3
  const int fr  = l & 15;
  const int lhi = l >> 4;   // 0..3

  int offA[4], offB[2];
  #pragma unroll
  for (int i = 0; i < 4; ++i) {
    const int ra = wr * 64 + i * 16 + fr;
    offA[i] = ra * 128 + ((lhi ^ (ra & 7)) << 4);   // kb=1 via ^64
  }
  #pragma unroll
  for (int j = 0; j < 2; ++j) {
    const int cb = wc * 32 + j * 16 + fr;
    offB[j] = cb * 128 + ((lhi ^ (cb & 7)) << 4);
  }

  f32x4 acc[4][2] = {};
  f32x4 sA0[4], sA1[4], sB[4];

#define ISSUE_A(S_, kt_)                                                    \
  do {                                                                      \
    const float* pa = gA + (size_t)(kt_)*BK;                                \
    _Pragma("unroll") for (int r = 0; r < 4; ++r)                           \
        S_[r] = __builtin_nontemporal_load(                                 \
            (const f32x4*)(pa + (size_t)r * 32 * K_DIM));                   \
  } while (0)

#define ISSUE_B(kt_)                                                        \
  do {                                                                      \
    const float* pb = gB + (size_t)(kt_)*BK;                                \
    _Pragma("unroll") for (int r = 0; r < 4; ++r)                           \
        sB[r] = *(const f32x4*)(pb + (size_t)r * 32 * K_DIM);               \
  } while (0)

#define STAGE_A(S_, buf_)                                                   \
  do {                                                                      \
    char* bA = (char*)ldsA + (buf_)*16384 + wb0;                            \
    _Pragma("unroll") for (int r = 0; r < 4; ++r) {                         \
      uint2 u;                                                              \
      u.x = pkbf(S_[r][0], S_[r][1]);                                       \
      u.y = pkbf(S_[r][2], S_[r][3]);                                       \
      *(uint2*)(bA + r * 4096) = u;                                         \
    }                                                                       \
  } while (0)

#define STAGE_B(buf_)                                                       \
  do {                                                                      \
    char* bB = (char*)ldsB + (buf_)*16384 + wb0;                            \
    _Pragma("unroll") for (int r = 0; r < 4; ++r) {                         \
      uint2 u;                                                              \
      u.x = pkbf(sB[r][0], sB[r][1]);                                       \
      u.y = pkbf(sB[r][2], sB[r][3]);                                       \
      *(uint2*)(bB + r * 4096) = u;                                         \
    }                                                                       \
  } while (0)

#define COMPUTE(buf_)                                                       \
  do {                                                                      \
    const char* bA = (const char*)ldsA + (buf_)*16384;                      \
    const char* bB = (const char*)ldsB + (buf_)*16384;                      \
    _Pragma("unroll") for (int kb = 0; kb < 2; ++kb) {                      \
      const int kx = kb * 64;                                               \
      short8 af[4], bg[2];                                                  \
      _Pragma("unroll") for (int i = 0; i < 4; ++i)                         \
          af[i] = *(const short8*)(bA + (offA[i] ^ kx));                    \
      _Pragma("unroll") for (int j = 0; j < 2; ++j)                         \
          bg[j] = *(const short8*)(bB + (offB[j] ^ kx));                    \
      _Pragma("unroll") for (int i = 0; i < 4; ++i)                         \
          _Pragma("unroll") for (int j = 0; j < 2; ++j)                     \
              acc[i][j] = __builtin_amdgcn_mfma_f32_16x16x32_bf16(          \
                  af[i], bg[j], acc[i][j], 0, 0, 0);                        \
    }                                                                       \
  } while (0)

  // prologue: A tiles 0,1 and B tile 0 in flight
  ISSUE_A(sA0, 0);
  ISSUE_A(sA1, 1);
  ISSUE_B(0);

  for (int kt = 0; kt < NT; kt += 2) {
    // ---- tile kt -> buf0. Wait on A(kt) issued 2 tiles ago (counted:
    // A(kt+1)+B leftovers stay in flight), B(kt) issued ~1 tile ago.
    STAGE_A(sA0, 0);
    STAGE_B(0);
    __syncthreads();
    ISSUE_B(kt + 1);                       // kt+1 < NT always (NT even)
    if (kt + 2 < NT) ISSUE_A(sA0, kt + 2);
    COMPUTE(0);
    // ---- tile kt+1 -> buf1
    STAGE_A(sA1, 1);
    STAGE_B(1);
    __syncthreads();
    if (kt + 2 < NT) {
      ISSUE_B(kt + 2);
      if (kt + 3 < NT) ISSUE_A(sA1, kt + 3);
    }
    COMPUTE(1);
  }

#undef ISSUE_A
#undef ISSUE_B
#undef STAGE_A
#undef STAGE_B
#undef COMPUTE

  // ---- epilogue: C/D layout col=lane&15, row=(lane>>4)*4+reg (m89-verified)
  if (!ATOMIC) {
    float* dst = part + (((size_t)mat * KSPLIT + ks) * B_ROWS) * (size_t)H_DIM;
    #pragma unroll
    for (int i = 0; i < 4; ++i)
      #pragma unroll
      for (int j = 0; j < 2; ++j)
        #pragma unroll
        for (int r = 0; r < 4; ++r) {
          const int rowg = mt * BM + wr * 64 + i * 16 + (lhi << 2) + r;
          const int colg = wc * 32 + j * 16 + fr;
          __builtin_nontemporal_store(acc[i][j][r],
                                      &dst[(size_t)rowg * H_DIM + colg]);
        }
  } else {
    float* dst = g_acc + (size_t)mat * B_ROWS * H_DIM;
    #pragma unroll
    for (int i = 0; i < 4; ++i)
      #pragma unroll
      for (int j = 0; j < 2; ++j)
        #pragma unroll
        for (int r = 0; r < 4; ++r) {
          const int rowg = mt * BM + wr * 64 + i * 16 + (lhi << 2) + r;
          const int colg = wc * 32 + j * 16 + fr;
          atomicAdd(&dst[(size_t)rowg * H_DIM + colg], acc[i][j][r]);
        }
  }
}

__global__ void nnue_zero_acc() {
  const unsigned i = blockIdx.x * 256 + threadIdx.x;
  if (i < 2u * B_ROWS * H_DIM) g_acc[i] = 0.f;
}

// one wave per output row; part==nullptr -> read g_acc (KS must be 1)
template <int KS>
__global__ __launch_bounds__(512) void nnue_stage2(
    const float* __restrict__ part, const float* __restrict__ w2,
    float* __restrict__ out) {
  const float* p = part ? part : (const float*)g_acc;
  const int t = threadIdx.x;
  const int l = t & 63, w = t >> 6;
  const int b = blockIdx.x * 8 + w;
  float a0 = 0.f, a1 = 0.f, a2 = 0.f, a3 = 0.f;
  #pragma unroll
  for (int ks = 0; ks < KS; ++ks) {
    const float* p0 = p + ((size_t)ks * B_ROWS + b) * H_DIM;
    const float* p1 = p + (((size_t)KS + ks) * B_ROWS + b) * H_DIM;
    a0 += __builtin_nontemporal_load(&p0[l]);
    a1 += __builtin_nontemporal_load(&p0[l + 64]);
    a2 += __builtin_nontemporal_load(&p1[l]);
    a3 += __builtin_nontemporal_load(&p1[l + 64]);
  }
  float sv = fmaxf(a0, 0.f) * w2[l] + fmaxf(a1, 0.f) * w2[l + 64] +
             fmaxf(a2, 0.f) * w2[l + 128] + fmaxf(a3, 0.f) * w2[l + 192];
  #pragma unroll
  for (int off = 32; off; off >>= 1) sv += __shfl_xor(sv, off, 64);
  if (l == 0) out[b] = sv;
}

extern "C" void kernel_launch(void* const* d_in, const int* in_sizes, int n_in,
                              void* d_out, int out_size, void* d_ws,
                              size_t ws_size, hipStream_t stream) {
  const float* x1    = (const float*)d_in[0];
  const float* x2    = (const float*)d_in[1];
  // d_in[2] = turn (unused by reference)
  const float* wus   = (const float*)d_in[3];
  const float* wthem = (const float*)d_in[4];
  const float* w2    = (const float*)d_in[5];
  float* out = (float*)d_out;

  const size_t PART_BYTES =
      2ull * KSPLIT * B_ROWS * H_DIM * sizeof(float);  // 33.6 MB

  if (ws_size >= PART_BYTES) {
    float* part = (float*)d_ws;
    nnue_stage1<false><<<MT * KSPLIT * 2, 512, 0, stream>>>(x1, x2, wus, wthem,
                                                            part);
    nnue_stage2<KSPLIT><<<B_ROWS / 8, 512, 0, stream>>>(part, w2, out);
  } else {
    nnue_zero_acc<<<(2 * B_ROWS * H_DIM + 255) / 256, 256, 0, stream>>>();
    nnue_stage1<true><<<MT * KSPLIT * 2, 512, 0, stream>>>(x1, x2, wus, wthem,
                                                           nullptr);
    nnue_stage2<1><<<B_ROWS / 8, 512, 0, stream>>>(nullptr, w2, out);
  }
}